// Round 14
// baseline (2187.311 us; speedup 1.0000x reference)
//
#include <hip/hip_runtime.h>
#include <stdint.h>

typedef unsigned int u32;
typedef short short8 __attribute__((ext_vector_type(8)));
typedef short bf16x8 __attribute__((ext_vector_type(8)));
typedef float f32x4  __attribute__((ext_vector_type(4)));

#define B_ROWS 8192
#define HID    1024
#define KDIM   3072
#define NGATE  5

// GEMM tile: 256 batch rows x (5 gates x 64 hidden) per block, 16 waves 4Mx4N,
// per-wave 64x80 (acc[4][5]=80, R11-proven). NEW vs R11: A-fragments are
// loaded DIRECTLY from global into registers (16B/lane, L1-served: the 4
// wn-wave-groups share the same 32 KiB A-tile = L1 size). LDS holds only B
// (2 x 40 KiB). LDS traffic/tile drops 360 -> 200 KiB (below the MFMA pipe),
// and the tile-end wait becomes counted vmcnt(8): only B-staging must land;
// the 8 A(t+1) prefetch loads stay in flight across the barrier (T4).
#define BM 256
#define BN 320
#define BK 64
#define NT (KDIM / BK)               // 48
#define LDSB_SH (BN * BK)            // 20480 shorts = 40 KiB
#define BUF_BYTES (LDSB_SH * 2)      // 40960

// ---------- helpers ----------
__device__ __forceinline__ short f2bf(float f) {
  u32 u = __builtin_bit_cast(u32, f);
  u += 0x7FFFu + ((u >> 16) & 1u);   // round-to-nearest-even
  return (short)(u >> 16);
}

__device__ __forceinline__ float sigf(float v) { return 1.0f / (1.0f + __expf(-v)); }

__device__ __forceinline__ void async_copy16(const void* g, void* l) {
  __builtin_amdgcn_global_load_lds(
      (__attribute__((address_space(1))) void*)(g),
      (__attribute__((address_space(3))) void*)(l),
      16, 0, 0);
}

// ---------- conversion kernels ----------
__global__ void convert_combined(const float* __restrict__ x,
                                 const float* __restrict__ hl,
                                 const float* __restrict__ hr,
                                 short* __restrict__ out) {
  const int total  = B_ROWS * (KDIM / 8);
  const int stride = gridDim.x * blockDim.x;
  for (int i = blockIdx.x * blockDim.x + threadIdx.x; i < total; i += stride) {
    int row = i / (KDIM / 8);
    int col = (i - row * (KDIM / 8)) * 8;
    const float* src;
    if (col < 1024)      src = x  + (int64_t)row * 1024 + col;
    else if (col < 2048) src = hl + (int64_t)row * 1024 + (col - 1024);
    else                 src = hr + (int64_t)row * 1024 + (col - 2048);
    float4 v0 = ((const float4*)src)[0];
    float4 v1 = ((const float4*)src)[1];
    short8 r;
    r[0] = f2bf(v0.x); r[1] = f2bf(v0.y); r[2] = f2bf(v0.z); r[3] = f2bf(v0.w);
    r[4] = f2bf(v1.x); r[5] = f2bf(v1.y); r[6] = f2bf(v1.z); r[7] = f2bf(v1.w);
    *(short8*)(out + (int64_t)row * KDIM + col) = r;
  }
}

__global__ void convert_w(const float* __restrict__ Wf, short* __restrict__ out) {
  const int total  = NGATE * HID * (KDIM / 8);
  const int stride = gridDim.x * blockDim.x;
  for (int i = blockIdx.x * blockDim.x + threadIdx.x; i < total; i += stride) {
    int64_t e = (int64_t)i * 8;
    float4 v0 = ((const float4*)(Wf + e))[0];
    float4 v1 = ((const float4*)(Wf + e))[1];
    short8 r;
    r[0] = f2bf(v0.x); r[1] = f2bf(v0.y); r[2] = f2bf(v0.z); r[3] = f2bf(v0.w);
    r[4] = f2bf(v1.x); r[5] = f2bf(v1.y); r[6] = f2bf(v1.z); r[7] = f2bf(v1.w);
    *(short8*)(out + e) = r;
  }
}

// ---------- fused GEMM + LSTM-cell epilogue (B-in-LDS, A-direct) ----------
// Per tile t: {stage B(t+1) -> other buf (2-3 gload_lds); bfr ds_reads from
// cur buf; 40 MFMA using a[8] (loaded last tile); issue A(t+1) -> a[8];
// lgkmcnt(0); vmcnt(8) [oldest 2-3 = B(t+1) landed; A(t+1) stays in flight
// across the barrier]; s_barrier}. LDS XOR-swizzle on B (slot s of row r at
// s^(r&7), source pre-swizzled, rule #21) -- proven 0-conflict.
__global__ __launch_bounds__(1024, 4) void lstm_gemm(
    const short* __restrict__ Abf,   // [8192][3072] bf16
    const short* __restrict__ Wbf,   // [5120][3072] bf16
    const float* __restrict__ bias,  // [5120]
    const float* __restrict__ c_left,
    const float* __restrict__ c_right,
    float* __restrict__ out) {       // h at 0, c at 8192*1024
  __shared__ short lds[2 * LDSB_SH];  // 80 KiB (B only)
  char* const ldsc = (char*)lds;

  const int tid = threadIdx.x;
  const int w  = tid >> 6;     // 0..15
  const int l  = tid & 63;
  const int wm = w >> 2;       // 0..3  (M group: 64 rows)
  const int wn = w & 3;        // 0..3  (N group: 16 hidden x 5 gates)
  const int lc = l & 15;
  const int khalf = l >> 4;    // 0..3

  // XCD-aware bijective swizzle (512 % 8 == 0)
  const int bid = blockIdx.x;
  const int wg  = (bid & 7) * 64 + (bid >> 3);
  const int m0  = (wg >> 4) * BM;
  const int j0  = (wg & 15) * 64;

  // ---- B staging (identical to R11): per wave-load 8 rows x 128B ----
  const int r8 = l >> 3;
  const int sl = (l & 7) ^ r8;      // pre-swizzled source slot
  u32 boff[3];
#pragma unroll
  for (int i = 0; i < 3; ++i) {
    int lb = w + 16 * i;
    if (lb < 40) {
      int rb = lb * 8 + r8;                          // 0..319
      int g  = (rb % 80) >> 4;
      int dj = (rb / 80) * 16 + (rb & 15);
      boff[i] = (u32)(g * HID + j0 + dj) * KDIM + sl * 8;
    } else boff[i] = boff[0];
  }

  // ---- A-direct per-lane element offsets: frag f = kk*4 + m ----
  u32 aoffA[8];
#pragma unroll
  for (int kk = 0; kk < 2; ++kk)
#pragma unroll
    for (int m = 0; m < 4; ++m)
      aoffA[kk * 4 + m] =
          (u32)(m0 + wm * 64 + m * 16 + lc) * KDIM + khalf * 8 + kk * 32;

  // ---- bfr ds_read byte addresses (buffer 0) ----
  const u32 sw0 = (u32)(((khalf    ) ^ (lc & 7)) * 16);
  const u32 sw1 = (u32)(((khalf + 4) ^ (lc & 7)) * 16);
  u32 bAd0 = (u32)((wn * 80 + lc) * 128) + sw0;
  u32 bAd1 = (u32)((wn * 80 + lc) * 128) + sw1;

  f32x4 acc[4][5];
  const f32x4 zero = {0.0f, 0.0f, 0.0f, 0.0f};
#pragma unroll
  for (int m = 0; m < 4; ++m)
#pragma unroll
    for (int n = 0; n < 5; ++n) acc[m][n] = zero;

  bf16x8 a[8];

  // ---- prologue: stage B(0) -> buf0; issue A(0); wait B only ----
#pragma unroll
  for (int i = 0; i < 2; ++i)
    async_copy16(Wbf + boff[i], lds + (w + 16 * i) * 512);
  if (w < 8)
    async_copy16(Wbf + boff[2], lds + (32 + w) * 512);
#pragma unroll
  for (int i = 0; i < 3; ++i) boff[i] += BK;
#pragma unroll
  for (int f = 0; f < 8; ++f) {
    a[f] = *(const bf16x8*)(Abf + aoffA[f]);
    aoffA[f] += BK;
  }
  asm volatile("s_waitcnt vmcnt(8)" ::: "memory");  // B(0) landed, A(0) flying
  __builtin_amdgcn_s_barrier();

  int bufd = BUF_BYTES;
  for (int t = 0; t < NT; ++t) {
    // ---- stage B(t+1) into the other buffer ----
    if (t < NT - 1) {
      short* dB = lds + ((t + 1) & 1) * LDSB_SH;
#pragma unroll
      for (int i = 0; i < 2; ++i)
        async_copy16(Wbf + boff[i], dB + (w + 16 * i) * 512);
      if (w < 8)
        async_copy16(Wbf + boff[2], dB + (32 + w) * 512);
#pragma unroll
      for (int i = 0; i < 3; ++i) boff[i] += BK;
    }

    // ---- compute: bfr from LDS, A from registers ----
    bf16x8 bfr[5][2];
#pragma unroll
    for (int g = 0; g < 5; ++g) {
      bfr[g][0] = *(const bf16x8*)(ldsc + bAd0 + g * 2048);
      bfr[g][1] = *(const bf16x8*)(ldsc + bAd1 + g * 2048);
    }
    __builtin_amdgcn_s_setprio(1);
#pragma unroll
    for (int kk = 0; kk < 2; ++kk)
#pragma unroll
      for (int m = 0; m < 4; ++m)
#pragma unroll
        for (int g = 0; g < 5; ++g)
          acc[m][g] = __builtin_amdgcn_mfma_f32_16x16x32_bf16(
              a[kk * 4 + m], bfr[g][kk], acc[m][g], 0, 0, 0);
    __builtin_amdgcn_s_setprio(0);

    // ---- prefetch A(t+1) into regs (after MFMA consumed a[]) ----
    if (t < NT - 1) {
#pragma unroll
      for (int f = 0; f < 8; ++f) {
        a[f] = *(const bf16x8*)(Abf + aoffA[f]);
        aoffA[f] += BK;
      }
    }

    // ---- tile boundary: B(t+1) landed (counted), A(t+1) stays in flight ----
    asm volatile("s_waitcnt lgkmcnt(0)" ::: "memory");
    if (t < NT - 1) asm volatile("s_waitcnt vmcnt(8)" ::: "memory");
    else            asm volatile("s_waitcnt vmcnt(0)" ::: "memory");
    __builtin_amdgcn_s_barrier();

    bAd0 += bufd; bAd1 += bufd;
    bufd = -bufd;
  }

  // ---- epilogue: 5 gates for (row, j) all live in this lane ----
  const int j = j0 + wn * 16 + lc;
  float bi[5];
#pragma unroll
  for (int g = 0; g < 5; ++g) bi[g] = bias[g * HID + j];
#pragma unroll
  for (int m = 0; m < 4; ++m) {
#pragma unroll
    for (int r = 0; r < 4; ++r) {
      const int row = m0 + wm * 64 + m * 16 + khalf * 4 + r;
      const int off = row * HID + j;
      float iv  = sigf(acc[m][0][r] + bi[0]);
      float flv = sigf(acc[m][1][r] + bi[1]);
      float frv = sigf(acc[m][2][r] + bi[2]);
      float ov  = sigf(acc[m][3][r] + bi[3]);
      float uv  = tanhf(acc[m][4][r] + bi[4]);
      float cv  = iv * uv + flv * c_left[off] + frv * c_right[off];
      out[off] = ov * tanhf(cv);
      out[B_ROWS * HID + off] = cv;
    }
  }
}

// ---------- fp32 fallback (only if ws too small) ----------
__global__ void lstm_fallback(const float* __restrict__ x, const float* __restrict__ hl,
                              const float* __restrict__ hr, const float* __restrict__ cl,
                              const float* __restrict__ cr, const float* __restrict__ W,
                              const float* __restrict__ b, float* __restrict__ out) {
  int64_t idx = (int64_t)blockIdx.x * blockDim.x + threadIdx.x;
  if (idx >= (int64_t)B_ROWS * HID) return;
  int bi = (int)(idx >> 10);
  int j  = (int)(idx & 1023);
  float acc[5];
#pragma unroll
  for (int g = 0; g < 5; ++g) acc[g] = b[g * HID + j];
  const float* segs[3] = {x + (int64_t)bi * 1024, hl + (int64_t)bi * 1024,
                          hr + (int64_t)bi * 1024};
  for (int s = 0; s < 3; ++s) {
    const float4* v = (const float4*)segs[s];
    for (int k4 = 0; k4 < 256; ++k4) {
      float4 a = v[k4];
#pragma unroll
      for (int g = 0; g < 5; ++g) {
        const float4 wv = *(const float4*)(W + (int64_t)(g * HID + j) * KDIM + s * 1024 + k4 * 4);
        acc[g] += a.x * wv.x + a.y * wv.y + a.z * wv.z + a.w * wv.w;
      }
    }
  }
  float iv = sigf(acc[0]), fl = sigf(acc[1]), fr = sigf(acc[2]), ov = sigf(acc[3]);
  float uv = tanhf(acc[4]);
  float cv = iv * uv + fl * cl[idx] + fr * cr[idx];
  out[idx] = ov * tanhf(cv);
  out[(int64_t)B_ROWS * HID + idx] = cv;
}

// ---------- host ----------
extern "C" void kernel_launch(void* const* d_in, const int* in_sizes, int n_in,
                              void* d_out, int out_size, void* d_ws, size_t ws_size,
                              hipStream_t stream) {
  const float* x  = (const float*)d_in[0];
  const float* hl = (const float*)d_in[1];
  const float* cl = (const float*)d_in[2];
  const float* hr = (const float*)d_in[3];
  const float* cr = (const float*)d_in[4];
  const float* W  = (const float*)d_in[5];
  const float* b  = (const float*)d_in[6];
  float* out = (float*)d_out;

  const size_t needA = (size_t)B_ROWS * KDIM * sizeof(short);      // 48 MiB
  const size_t needW = (size_t)NGATE * HID * KDIM * sizeof(short); // 30 MiB

  if (ws_size >= needA + needW) {
    short* Abf = (short*)d_ws;
    short* Wbf = (short*)((char*)d_ws + needA);
    convert_combined<<<2048, 256, 0, stream>>>(x, hl, hr, Abf);
    convert_w<<<2048, 256, 0, stream>>>(W, Wbf);
    lstm_gemm<<<512, 1024, 0, stream>>>(Abf, Wbf, b, cl, cr, out);
  } else {
    lstm_fallback<<<(B_ROWS * HID) / 256, 256, 0, stream>>>(x, hl, hr, cl, cr, W, b, out);
  }
}

// Round 15
// 272.665 us; speedup vs baseline: 8.0220x; 8.0220x over previous
//
#include <hip/hip_runtime.h>
#include <stdint.h>

typedef unsigned int u32;
typedef short short8 __attribute__((ext_vector_type(8)));
typedef short bf16x8 __attribute__((ext_vector_type(8)));
typedef float f32x4  __attribute__((ext_vector_type(4)));

#define B_ROWS 8192
#define HID    1024
#define KDIM   3072
#define NGATE  5

// GEMM tile: 256 batch rows x (5 gates x 64 hidden) per block.
// 16 waves (1024 thr) as 4M x 4N: per-wave output 64 rows x 80 cols
// = acc[4][5] = 80 regs; B-frags held per-kk only (20 regs) -> live set
// ~120 < 128-reg unified VGPR+AGPR cap at 4 waves/SIMD. (R14 lesson: the
// AGPR acc COUNTS against the same 128; adding bfr[5][2]+a[8] spilled.)
// BK=64, proven 8-slot XOR swizzle (0 conflicts), drift schedule (1
// barrier/tile). This is the R11 champion config: 242 us, MfmaUtil 49%.
#define BM 256
#define BN 320
#define BK 64
#define NT (KDIM / BK)               // 48
#define LDSA_SH (BM * BK)            // 16384 shorts
#define LDSB_SH (BN * BK)            // 20480 shorts
#define BUF_SH  (LDSA_SH + LDSB_SH)  // 36864 shorts = 72 KiB
#define BUF_BYTES (BUF_SH * 2)       // 73728

// ---------- helpers ----------
__device__ __forceinline__ short f2bf(float f) {
  u32 u = __builtin_bit_cast(u32, f);
  u += 0x7FFFu + ((u >> 16) & 1u);   // round-to-nearest-even
  return (short)(u >> 16);
}

__device__ __forceinline__ float sigf(float v) { return 1.0f / (1.0f + __expf(-v)); }

// stable fast tanh: t=e^(-2|x|) in (0,1], r=(1-t)/(1+t), sign-restored.
__device__ __forceinline__ float ftanh(float x) {
  float a = fabsf(x);
  float t = __expf(-2.0f * a);
  float r = (1.0f - t) / (1.0f + t);
  return x < 0.0f ? -r : r;
}

__device__ __forceinline__ void async_copy16(const void* g, void* l) {
  __builtin_amdgcn_global_load_lds(
      (__attribute__((address_space(1))) void*)(g),
      (__attribute__((address_space(3))) void*)(l),
      16, 0, 0);
}

// ---------- conversion kernels ----------
__global__ void convert_combined(const float* __restrict__ x,
                                 const float* __restrict__ hl,
                                 const float* __restrict__ hr,
                                 short* __restrict__ out) {
  const int total  = B_ROWS * (KDIM / 8);
  const int stride = gridDim.x * blockDim.x;
  for (int i = blockIdx.x * blockDim.x + threadIdx.x; i < total; i += stride) {
    int row = i / (KDIM / 8);
    int col = (i - row * (KDIM / 8)) * 8;
    const float* src;
    if (col < 1024)      src = x  + (int64_t)row * 1024 + col;
    else if (col < 2048) src = hl + (int64_t)row * 1024 + (col - 1024);
    else                 src = hr + (int64_t)row * 1024 + (col - 2048);
    float4 v0 = ((const float4*)src)[0];
    float4 v1 = ((const float4*)src)[1];
    short8 r;
    r[0] = f2bf(v0.x); r[1] = f2bf(v0.y); r[2] = f2bf(v0.z); r[3] = f2bf(v0.w);
    r[4] = f2bf(v1.x); r[5] = f2bf(v1.y); r[6] = f2bf(v1.z); r[7] = f2bf(v1.w);
    *(short8*)(out + (int64_t)row * KDIM + col) = r;
  }
}

__global__ void convert_w(const float* __restrict__ Wf, short* __restrict__ out) {
  const int total  = NGATE * HID * (KDIM / 8);
  const int stride = gridDim.x * blockDim.x;
  for (int i = blockIdx.x * blockDim.x + threadIdx.x; i < total; i += stride) {
    int64_t e = (int64_t)i * 8;
    float4 v0 = ((const float4*)(Wf + e))[0];
    float4 v1 = ((const float4*)(Wf + e))[1];
    short8 r;
    r[0] = f2bf(v0.x); r[1] = f2bf(v0.y); r[2] = f2bf(v0.z); r[3] = f2bf(v0.w);
    r[4] = f2bf(v1.x); r[5] = f2bf(v1.y); r[6] = f2bf(v1.z); r[7] = f2bf(v1.w);
    *(short8*)(out + e) = r;
  }
}

// ---------- fused GEMM + LSTM-cell epilogue ----------
// Drift schedule: stage t+1 at tile start into the other buffer; no
// intra-tile barriers; one vmcnt(0)+lgkmcnt(0)+s_barrier per tile.
// LDS XOR-swizzle: slot s of row r at s^(r&7); source pre-swizzled (rule #21).
__global__ __launch_bounds__(1024, 4) void lstm_gemm(
    const short* __restrict__ Abf,   // [8192][3072] bf16
    const short* __restrict__ Wbf,   // [5120][3072] bf16
    const float* __restrict__ bias,  // [5120]
    const float* __restrict__ c_left,
    const float* __restrict__ c_right,
    float* __restrict__ out) {       // h at 0, c at 8192*1024
  __shared__ short lds[2 * BUF_SH];  // 144 KiB
  char* const ldsc = (char*)lds;

  const int tid = threadIdx.x;
  const int w  = tid >> 6;     // 0..15
  const int l  = tid & 63;
  const int wm = w >> 2;       // 0..3  (M group: 64 rows)
  const int wn = w & 3;        // 0..3  (N group: 16 hidden cols x 5 gates)
  const int lc = l & 15;
  const int khalf = l >> 4;    // 0..3

  // XCD-aware bijective swizzle (512 % 8 == 0)
  const int bid = blockIdx.x;
  const int wg  = (bid & 7) * 64 + (bid >> 3);
  const int m0  = (wg >> 4) * BM;
  const int j0  = (wg & 15) * 64;

  // staging: per wave-load 8 rows x 128B; lane l -> row += l>>3, slot l&7
  const int r8 = l >> 3;
  const int sl = (l & 7) ^ r8;      // pre-swizzled source slot
  // A: 32 loads -> wave w takes n = 2w, 2w+1 (rows [8n, 8n+8))
  u32 aoff[2];
#pragma unroll
  for (int i = 0; i < 2; ++i)
    aoff[i] = (u32)(m0 + (2 * w + i) * 8 + r8) * KDIM + sl * 8;
  // B: 40 loads -> wave w takes lb = w, 16+w, and (w<8) 32+w
  u32 boff[3];
#pragma unroll
  for (int i = 0; i < 3; ++i) {
    int lb = w + 16 * i;
    if (lb < 40) {
      int rb = lb * 8 + r8;                          // 0..319
      int g  = (rb % 80) >> 4;
      int dj = (rb / 80) * 16 + (rb & 15);
      boff[i] = (u32)(g * HID + j0 + dj) * KDIM + sl * 8;
    } else boff[i] = boff[0];
  }

  // ds_read byte addresses (buffer 0); row&7 == lc&7 since rows are 16k+lc
  const u32 sw0 = (u32)(((khalf    ) ^ (lc & 7)) * 16);
  const u32 sw1 = (u32)(((khalf + 4) ^ (lc & 7)) * 16);
  u32 aAd0 = (u32)((wm * 64 + lc) * 128) + sw0;
  u32 aAd1 = (u32)((wm * 64 + lc) * 128) + sw1;
  u32 bAd0 = (u32)(LDSA_SH * 2) + (u32)((wn * 80 + lc) * 128) + sw0;
  u32 bAd1 = (u32)(LDSA_SH * 2) + (u32)((wn * 80 + lc) * 128) + sw1;

  f32x4 acc[4][5];
  const f32x4 zero = {0.0f, 0.0f, 0.0f, 0.0f};
#pragma unroll
  for (int m = 0; m < 4; ++m)
#pragma unroll
    for (int n = 0; n < 5; ++n) acc[m][n] = zero;

  // ---- prologue: stage tile 0 into buffer 0 ----
#pragma unroll
  for (int i = 0; i < 2; ++i)
    async_copy16(Abf + aoff[i], lds + (2 * w + i) * 512);
#pragma unroll
  for (int i = 0; i < 2; ++i)
    async_copy16(Wbf + boff[i], lds + LDSA_SH + (w + 16 * i) * 512);
  if (w < 8)
    async_copy16(Wbf + boff[2], lds + LDSA_SH + (32 + w) * 512);
#pragma unroll
  for (int i = 0; i < 2; ++i) aoff[i] += BK;
#pragma unroll
  for (int i = 0; i < 3; ++i) boff[i] += BK;
  asm volatile("s_waitcnt vmcnt(0)" ::: "memory");
  __builtin_amdgcn_s_barrier();

  int bufd = BUF_BYTES;
  for (int t = 0; t < NT; ++t) {
    // ---- stage t+1 into the other buffer ----
    if (t < NT - 1) {
      short* dA = lds + ((t + 1) & 1) * BUF_SH;
      short* dB = dA + LDSA_SH;
#pragma unroll
      for (int i = 0; i < 2; ++i)
        async_copy16(Abf + aoff[i], dA + (2 * w + i) * 512);
#pragma unroll
      for (int i = 0; i < 2; ++i)
        async_copy16(Wbf + boff[i], dB + (w + 16 * i) * 512);
      if (w < 8)
        async_copy16(Wbf + boff[2], dB + (32 + w) * 512);
#pragma unroll
      for (int i = 0; i < 2; ++i) aoff[i] += BK;
#pragma unroll
      for (int i = 0; i < 3; ++i) boff[i] += BK;
    }

    // ---- compute: kk0 then kk1; B-frags per-kk (20 regs), af per m ----
    __builtin_amdgcn_s_setprio(1);
    {
      bf16x8 bfr[5];
#pragma unroll
      for (int g = 0; g < 5; ++g)
        bfr[g] = *(const bf16x8*)(ldsc + bAd0 + g * 2048);
#pragma unroll
      for (int m = 0; m < 4; ++m) {
        bf16x8 af = *(const bf16x8*)(ldsc + aAd0 + m * 2048);
#pragma unroll
        for (int g = 0; g < 5; ++g)
          acc[m][g] = __builtin_amdgcn_mfma_f32_16x16x32_bf16(
              af, bfr[g], acc[m][g], 0, 0, 0);
      }
    }
    {
      bf16x8 bfr[5];
#pragma unroll
      for (int g = 0; g < 5; ++g)
        bfr[g] = *(const bf16x8*)(ldsc + bAd1 + g * 2048);
#pragma unroll
      for (int m = 0; m < 4; ++m) {
        bf16x8 af = *(const bf16x8*)(ldsc + aAd1 + m * 2048);
#pragma unroll
        for (int g = 0; g < 5; ++g)
          acc[m][g] = __builtin_amdgcn_mfma_f32_16x16x32_bf16(
              af, bfr[g], acc[m][g], 0, 0, 0);
      }
    }
    __builtin_amdgcn_s_setprio(0);

    // ---- tile boundary: staging landed, my reads drained, then sync ----
    asm volatile("s_waitcnt vmcnt(0) lgkmcnt(0)" ::: "memory");
    __builtin_amdgcn_s_barrier();

    aAd0 += bufd; aAd1 += bufd; bAd0 += bufd; bAd1 += bufd;
    bufd = -bufd;
  }

  // ---- epilogue: 5 gates for (row, j) all live in this lane ----
  const int j = j0 + wn * 16 + lc;
  float bi[5];
#pragma unroll
  for (int g = 0; g < 5; ++g) bi[g] = bias[g * HID + j];
#pragma unroll
  for (int m = 0; m < 4; ++m) {
#pragma unroll
    for (int r = 0; r < 4; ++r) {
      const int row = m0 + wm * 64 + m * 16 + khalf * 4 + r;
      const int off = row * HID + j;
      float iv  = sigf(acc[m][0][r] + bi[0]);
      float flv = sigf(acc[m][1][r] + bi[1]);
      float frv = sigf(acc[m][2][r] + bi[2]);
      float ov  = sigf(acc[m][3][r] + bi[3]);
      float uv  = ftanh(acc[m][4][r] + bi[4]);
      float cv  = iv * uv + flv * c_left[off] + frv * c_right[off];
      out[off] = ov * ftanh(cv);
      out[B_ROWS * HID + off] = cv;
    }
  }
}

// ---------- fp32 fallback (only if ws too small) ----------
__global__ void lstm_fallback(const float* __restrict__ x, const float* __restrict__ hl,
                              const float* __restrict__ hr, const float* __restrict__ cl,
                              const float* __restrict__ cr, const float* __restrict__ W,
                              const float* __restrict__ b, float* __restrict__ out) {
  int64_t idx = (int64_t)blockIdx.x * blockDim.x + threadIdx.x;
  if (idx >= (int64_t)B_ROWS * HID) return;
  int bi = (int)(idx >> 10);
  int j  = (int)(idx & 1023);
  float acc[5];
#pragma unroll
  for (int g = 0; g < 5; ++g) acc[g] = b[g * HID + j];
  const float* segs[3] = {x + (int64_t)bi * 1024, hl + (int64_t)bi * 1024,
                          hr + (int64_t)bi * 1024};
  for (int s = 0; s < 3; ++s) {
    const float4* v = (const float4*)segs[s];
    for (int k4 = 0; k4 < 256; ++k4) {
      float4 a = v[k4];
#pragma unroll
      for (int g = 0; g < 5; ++g) {
        const float4 wv = *(const float4*)(W + (int64_t)(g * HID + j) * KDIM + s * 1024 + k4 * 4);
        acc[g] += a.x * wv.x + a.y * wv.y + a.z * wv.z + a.w * wv.w;
      }
    }
  }
  float iv = sigf(acc[0]), fl = sigf(acc[1]), fr = sigf(acc[2]), ov = sigf(acc[3]);
  float uv = tanhf(acc[4]);
  float cv = iv * uv + fl * cl[idx] + fr * cr[idx];
  out[idx] = ov * tanhf(cv);
  out[(int64_t)B_ROWS * HID + idx] = cv;
}

// ---------- host ----------
extern "C" void kernel_launch(void* const* d_in, const int* in_sizes, int n_in,
                              void* d_out, int out_size, void* d_ws, size_t ws_size,
                              hipStream_t stream) {
  const float* x  = (const float*)d_in[0];
  const float* hl = (const float*)d_in[1];
  const float* cl = (const float*)d_in[2];
  const float* hr = (const float*)d_in[3];
  const float* cr = (const float*)d_in[4];
  const float* W  = (const float*)d_in[5];
  const float* b  = (const float*)d_in[6];
  float* out = (float*)d_out;

  const size_t needA = (size_t)B_ROWS * KDIM * sizeof(short);      // 48 MiB
  const size_t needW = (size_t)NGATE * HID * KDIM * sizeof(short); // 30 MiB

  if (ws_size >= needA + needW) {
    short* Abf = (short*)d_ws;
    short* Wbf = (short*)((char*)d_ws + needA);
    convert_combined<<<2048, 256, 0, stream>>>(x, hl, hr, Abf);
    convert_w<<<2048, 256, 0, stream>>>(W, Wbf);
    lstm_gemm<<<512, 1024, 0, stream>>>(Abf, Wbf, b, cl, cr, out);
  } else {
    lstm_fallback<<<(B_ROWS * HID) / 256, 256, 0, stream>>>(x, hl, hr, cl, cr, W, b, out);
  }
}